// Round 1
// 266.131 us; speedup vs baseline: 1.0814x; 1.0814x over previous
//
#include <hip/hip_runtime.h>
#include <math.h>

#define N 4
#define V 5
#define C 128
#define H 128
#define W 128
#define P 4096
#define HW (H * W)
#define PTS 16              // points per sample block
#define PCH 8               // point chunks per (n,v) in projection kernel
#define PPB (P / PCH)       // 512 points per projection block

typedef float  fvec4 __attribute__((ext_vector_type(4)));
typedef unsigned short usvec4 __attribute__((ext_vector_type(4)));

__device__ __forceinline__ unsigned short f2bf_rne(float x) {
    unsigned u = __float_as_uint(x);
    unsigned rounding = 0x7fffu + ((u >> 16) & 1u);
    return (unsigned short)((u + rounding) >> 16);
}
__device__ __forceinline__ float bf2f(unsigned short b) {
    return __uint_as_float(((unsigned)b) << 16);
}

// ---------------------------------------------------------------------------
// Kernel 1: projection. One block per (n,v, point-chunk). Computes the four
// clamped corner indices + bilinear weights + bound flag for each point-view
// and a per-block bbox over the clamped corners. No atomics: PCH partial
// bboxes per view, combined (scalar) by the transpose kernel.
// Every texel the gather can read is inside the bbox by construction.
// ---------------------------------------------------------------------------
__global__ __launch_bounds__(256) void project_kernel(
    const float* __restrict__ sp,      // (N,P,5)
    const float* __restrict__ Rm,      // (N,V,3,3)
    const float* __restrict__ Tm,      // (N,V,3)
    const float* __restrict__ fv,      // (N,V,2)
    const float* __restrict__ cv,      // (N,V,2)
    const float* __restrict__ kv,      // (N,V,3)
    const float* __restrict__ pv,      // (N,V,2)
    const float* __restrict__ trans,   // (N,V,2,3)
    const float* __restrict__ wh,      // (N,V,2)
    const float* __restrict__ fmsz,    // (2,)
    int4*   __restrict__ ws_idx,       // (N,P,V) corner indices
    float4* __restrict__ ws_w,         // (N,P,V) corner weights
    float*  __restrict__ ws_bnd,       // (N,P,V) bound flag
    int4*   __restrict__ ws_bbox)      // (N*V, PCH) partial bboxes
{
    const int nv = blockIdx.x;           // 0..N*V-1
    const int ch = blockIdx.y;           // 0..PCH-1
    const int n  = nv / V;
    const int t  = threadIdx.x;

    // uniform camera params (scalar loads)
    const float* Rv = Rm + nv * 9;
    const float R0 = Rv[0], R1 = Rv[1], R2 = Rv[2];
    const float R3 = Rv[3], R4 = Rv[4], R5 = Rv[5];
    const float R6 = Rv[6], R7 = Rv[7], R8 = Rv[8];
    const float tx = Tm[nv * 3 + 0], ty = Tm[nv * 3 + 1], tz = Tm[nv * 3 + 2];
    const float fx = fv[nv * 2 + 0], fy = fv[nv * 2 + 1];
    const float cx = cv[nv * 2 + 0], cy = cv[nv * 2 + 1];
    const float k1 = kv[nv * 3 + 0], k2 = kv[nv * 3 + 1], k3 = kv[nv * 3 + 2];
    const float p1 = pv[nv * 2 + 0], p2 = pv[nv * 2 + 1];
    const float* tr = trans + nv * 6;
    const float t0 = tr[0], t1 = tr[1], t2 = tr[2];
    const float t3 = tr[3], t4 = tr[4], t5 = tr[5];
    const float width  = wh[nv * 2 + 0];
    const float height = wh[nv * 2 + 1];
    const float maxwh  = fmaxf(width, height);
    const float fm0 = fmsz[0], fm1 = fmsz[1];
    const int v = nv - n * V;

    int minx = W - 1, maxx = 0, miny = H - 1, maxy = 0;

    #pragma unroll
    for (int k = 0; k < PPB / 256; ++k) {
        const int p  = ch * PPB + k * 256 + t;
        const int gp = n * P + p;
        const float X = sp[gp * 5 + 0];
        const float Y = sp[gp * 5 + 1];
        const float Z = sp[gp * 5 + 2];

        const float px = X - tx, py = Y - ty, pz = Z - tz;
        const float Xc0 = R0 * px + R1 * py + R2 * pz;
        const float Xc1 = R3 * px + R4 * py + R5 * pz;
        const float Xc2 = R6 * px + R7 * py + R8 * pz;
        const float xn = Xc0 / Xc2;
        const float yn = Xc1 / Xc2;
        const float r2 = xn * xn + yn * yn;
        const float radial = 1.0f + k1 * r2 + k2 * r2 * r2 + k3 * r2 * r2 * r2;
        const float xd = xn * radial + 2.0f * p1 * xn * yn + p2 * (r2 + 2.0f * xn * xn);
        const float yd = yn * radial + p1 * (r2 + 2.0f * yn * yn) + 2.0f * p2 * xn * yn;
        const float xy0 = xd * fx + cx;
        const float xy1 = yd * fy + cy;
        const bool bound = (xy0 >= 0.0f) && (xy1 >= 0.0f) && (xy0 < width) && (xy1 < height);
        const float pix0 = fminf(fmaxf(xy0, -1.0f), maxwh);
        const float pix1 = fminf(fmaxf(xy1, -1.0f), maxwh);
        const float pt0 = t0 * pix0 + t1 * pix1 + t2;
        const float pt1 = t3 * pix0 + t4 * pix1 + t5;
        float g0 = pt0 / (fm0 - 1.0f) * 2.0f - 1.0f;
        float g1 = pt1 / (fm1 - 1.0f) * 2.0f - 1.0f;
        g0 = fminf(fmaxf(g0, -1.1f), 1.1f);
        g1 = fminf(fmaxf(g1, -1.1f), 1.1f);

        const float xg = (g0 + 1.0f) * 0.5f * (float)(W - 1);
        const float yg = (g1 + 1.0f) * 0.5f * (float)(H - 1);
        const float x0f = floorf(xg), y0f = floorf(yg);
        const float wx1 = xg - x0f, wx0 = 1.0f - wx1;
        const float wy1 = yg - y0f, wy0 = 1.0f - wy1;
        const int x0 = (int)x0f, y0 = (int)y0f;
        const int x1 = x0 + 1,  y1 = y0 + 1;
        const bool vx0 = (x0 >= 0) && (x0 <= W - 1);
        const bool vx1 = (x1 >= 0) && (x1 <= W - 1);
        const bool vy0 = (y0 >= 0) && (y0 <= H - 1);
        const bool vy1 = (y1 >= 0) && (y1 <= H - 1);
        const int x0c = min(max(x0, 0), W - 1);
        const int x1c = min(max(x1, 0), W - 1);
        const int y0c = min(max(y0, 0), H - 1);
        const int y1c = min(max(y1, 0), H - 1);

        ws_idx[(size_t)gp * V + v] = make_int4(
            y0c * W + x0c, y0c * W + x1c, y1c * W + x0c, y1c * W + x1c);
        ws_w[(size_t)gp * V + v] = make_float4(
            (vx0 && vy0) ? (wx0 * wy0) : 0.0f,
            (vx1 && vy0) ? (wx1 * wy0) : 0.0f,
            (vx0 && vy1) ? (wx0 * wy1) : 0.0f,
            (vx1 && vy1) ? (wx1 * wy1) : 0.0f);
        ws_bnd[(size_t)gp * V + v] = bound ? 1.0f : 0.0f;

        minx = min(minx, x0c); maxx = max(maxx, x1c);
        miny = min(miny, y0c); maxy = max(maxy, y1c);
    }

    // block reduce bbox
    __shared__ int ra[256], rb[256], rc[256], rd[256];
    ra[t] = minx; rb[t] = maxx; rc[t] = miny; rd[t] = maxy;
    __syncthreads();
    for (int s = 128; s > 0; s >>= 1) {
        if (t < s) {
            ra[t] = min(ra[t], ra[t + s]);
            rb[t] = max(rb[t], rb[t + s]);
            rc[t] = min(rc[t], rc[t + s]);
            rd[t] = max(rd[t], rd[t + s]);
        }
        __syncthreads();
    }
    if (t == 0) ws_bbox[nv * PCH + ch] = make_int4(ra[0], rb[0], rc[0], rd[0]);
}

// ---------------------------------------------------------------------------
// Kernel 2: bbox-gated transpose (N,V,C,H,W) f32 -> (N,V,H,W,C) bf16.
// Tile: 32 hw (quarter row) x 128 c. Fixed grid (graph-capture safe);
// tiles outside the view's bbox exit immediately. Worst case = full map.
// ---------------------------------------------------------------------------
__global__ __launch_bounds__(256) void transpose_kernel(
    const float* __restrict__ fm, unsigned short* __restrict__ fmT,
    const int4* __restrict__ ws_bbox)
{
    const int nv   = blockIdx.y;         // 0..N*V-1
    const int tile = blockIdx.x;         // 0..511 (quarter rows)
    const int y  = tile >> 2;
    const int xq = (tile & 3) * 32;

    // combine partial bboxes (uniform scalar loads)
    int minx = W - 1, maxx = 0, miny = H - 1, maxy = 0;
    const int4* bb = ws_bbox + nv * PCH;
    #pragma unroll
    for (int i = 0; i < PCH; ++i) {
        const int4 b = bb[i];
        minx = min(minx, b.x); maxx = max(maxx, b.y);
        miny = min(miny, b.z); maxy = max(maxy, b.w);
    }
    if (y < miny || y > maxy || xq > maxx || xq + 31 < minx) return;

    __shared__ float lds[32][C + 1];     // +1 pad breaks power-of-2 stride
    const int t   = threadIdx.x;
    const int hw0 = y * W + xq;

    // Load: thread covers 4 consecutive hw at one c; 32 c per pass, 4 passes.
    {
        const int hwl = (t & 7) * 4;
        const int cb  = t >> 3;          // 0..31
        const float* src = fm + (size_t)nv * C * HW + hw0 + hwl;
        for (int c = cb; c < C; c += 32) {
            const fvec4 vv = __builtin_nontemporal_load(
                (const fvec4*)(src + (size_t)c * HW));
            lds[hwl + 0][c] = vv.x;
            lds[hwl + 1][c] = vv.y;
            lds[hwl + 2][c] = vv.z;
            lds[hwl + 3][c] = vv.w;
        }
    }
    __syncthreads();

    // Store: thread covers 4 consecutive c at one hw; 8 hw per pass, 4 passes.
    {
        const int c4 = (t & 31) * 4;
        unsigned short* dst = fmT + ((size_t)nv * HW + hw0) * C + c4;
        for (int hw = (t >> 5); hw < 32; hw += 8) {
            const fvec4 vv = *(const fvec4*)&lds[hw][c4];
            usvec4 o;
            o.x = f2bf_rne(vv.x);
            o.y = f2bf_rne(vv.y);
            o.z = f2bf_rne(vv.z);
            o.w = f2bf_rne(vv.w);
            *(usvec4*)(dst + (size_t)hw * C) = o;
        }
    }
}

// ---------------------------------------------------------------------------
// Kernel 3: gather from bf16 channel-last maps using precomputed idx/weights.
// Block = 256 threads, 16 points. 32 threads per point-view, 4 channels each;
// 8 point-views in flight, 10 iterations.
// ---------------------------------------------------------------------------
__global__ __launch_bounds__(256) void sample_kernel(
    const unsigned short* __restrict__ fmT, // (N,V,H,W,C) bf16
    const float* __restrict__ sp,           // (N,P,5)
    const int4*   __restrict__ ws_idx,      // (N,P,V)
    const float4* __restrict__ ws_w,        // (N,P,V)
    const float*  __restrict__ ws_bnd,      // (N,P,V)
    float* __restrict__ out_feats,          // (N,P,V,C)
    float* __restrict__ out_bound,          // (N,P)
    float* __restrict__ out_sp)             // (N,P,5)
{
    const int pb = blockIdx.x;               // 0 .. N*(P/PTS)-1
    const int n  = pb >> 8;                  // P/PTS = 256
    const int p0 = (pb & 255) * PTS;
    const int t  = threadIdx.x;
    const int base_pt = n * P + p0;

    __shared__ int4   s_idx[PTS * V];
    __shared__ float4 s_w[PTS * V];
    __shared__ float  s_bnd[PTS * V];
    __shared__ int    s_nan[PTS];

    if (t < PTS) s_nan[t] = 0;
    if (t < PTS * 5) out_sp[base_pt * 5 + t] = sp[base_pt * 5 + t];
    if (t < PTS * V) {
        s_idx[t] = ws_idx[(size_t)base_pt * V + t];
        s_w[t]   = ws_w[(size_t)base_pt * V + t];
        s_bnd[t] = ws_bnd[(size_t)base_pt * V + t];
    }
    __syncthreads();

    {
        const int grp = t >> 5;          // 0..7 point-view group
        const int c4  = (t & 31) * 4;    // channel base
        const unsigned short* img_n = fmT + (size_t)(n * V) * HW * C;
        #pragma unroll 2
        for (int i = grp; i < PTS * V; i += 8) {
            const int pt = i / V;
            const int v  = i - pt * V;
            const unsigned short* img = img_n + (size_t)v * HW * C + c4;
            const int4 ix = s_idx[i];
            const usvec4 b00 = *(const usvec4*)(img + (size_t)ix.x * C);
            const usvec4 b10 = *(const usvec4*)(img + (size_t)ix.y * C);
            const usvec4 b01 = *(const usvec4*)(img + (size_t)ix.z * C);
            const usvec4 b11 = *(const usvec4*)(img + (size_t)ix.w * C);
            const float4 wv = s_w[i];
            const float w00 = wv.x, w10 = wv.y, w01 = wv.z, w11 = wv.w;
            const float bnd = s_bnd[i];
            fvec4 f;
            f.x = (bf2f(b00.x) * w00 + bf2f(b10.x) * w10
                 + bf2f(b01.x) * w01 + bf2f(b11.x) * w11) * bnd;
            f.y = (bf2f(b00.y) * w00 + bf2f(b10.y) * w10
                 + bf2f(b01.y) * w01 + bf2f(b11.y) * w11) * bnd;
            f.z = (bf2f(b00.z) * w00 + bf2f(b10.z) * w10
                 + bf2f(b01.z) * w01 + bf2f(b11.z) * w11) * bnd;
            f.w = (bf2f(b00.w) * w00 + bf2f(b10.w) * w10
                 + bf2f(b01.w) * w01 + bf2f(b11.w) * w11) * bnd;
            if ((f.x != f.x) | (f.y != f.y) | (f.z != f.z) | (f.w != f.w))
                s_nan[pt] = 1;           // benign race
            __builtin_nontemporal_store(
                f, (fvec4*)&out_feats[((size_t)(base_pt + pt) * V + v) * C + c4]);
        }
    }
    __syncthreads();

    if (t < PTS) {
        bool any_b = false;
        #pragma unroll
        for (int v = 0; v < V; ++v) any_b |= (s_bnd[t * V + v] != 0.0f);
        out_bound[base_pt + t] = (any_b && (s_nan[t] == 0)) ? 1.0f : 0.0f;
    }
}

extern "C" void kernel_launch(void* const* d_in, const int* in_sizes, int n_in,
                              void* d_out, int out_size, void* d_ws, size_t ws_size,
                              hipStream_t stream) {
    const float* fm    = (const float*)d_in[0];
    const float* sp    = (const float*)d_in[1];
    const float* Rm    = (const float*)d_in[2];
    const float* Tm    = (const float*)d_in[3];
    const float* fv    = (const float*)d_in[4];
    const float* cv    = (const float*)d_in[5];
    const float* kv    = (const float*)d_in[6];
    const float* pv    = (const float*)d_in[7];
    const float* trans = (const float*)d_in[8];
    const float* wh    = (const float*)d_in[9];
    const float* fmsz  = (const float*)d_in[10];

    float* out        = (float*)d_out;
    float* out_feats  = out;
    float* out_bound  = out + (size_t)N * P * V * C;
    float* out_sp     = out_bound + (size_t)N * P;

    // workspace layout (all 16-B aligned)
    char* ws = (char*)d_ws;
    unsigned short* fmT = (unsigned short*)ws;               // 83.9 MB
    size_t off = (size_t)N * V * HW * C * sizeof(unsigned short);
    int4* ws_idx = (int4*)(ws + off);   off += (size_t)N * P * V * sizeof(int4);
    float4* ws_w = (float4*)(ws + off); off += (size_t)N * P * V * sizeof(float4);
    float* ws_bnd = (float*)(ws + off); off += (size_t)N * P * V * sizeof(float);
    int4* ws_bbox = (int4*)(ws + off);                       // (N*V, PCH)

    project_kernel<<<dim3(N * V, PCH), 256, 0, stream>>>(
        sp, Rm, Tm, fv, cv, kv, pv, trans, wh, fmsz,
        ws_idx, ws_w, ws_bnd, ws_bbox);

    transpose_kernel<<<dim3(HW / 32, N * V), 256, 0, stream>>>(fm, fmT, ws_bbox);

    sample_kernel<<<N * (P / PTS), 256, 0, stream>>>(
        fmT, sp, ws_idx, ws_w, ws_bnd, out_feats, out_bound, out_sp);
}